// Round 4
// baseline (164.532 us; speedup 1.0000x reference)
//
#include <hip/hip_runtime.h>
#include <hip/hip_bf16.h>
#include <stdint.h>

// LocalSlidingWindowAttention: B=2, T=2048, D=1024, H=16, hd=64, keys j in [i, i+64].
// f32 inputs/outputs. Pipeline: convert_all -> GEMM1 (qkv, 128x128) -> MFMA attention
// -> GEMM2 (64x128, 2 blocks/CU). Both GEMMs accumulate C^T (swapped MFMA operands) so
// each lane holds 4 consecutive n -> vectorized packed stores.

typedef short bf16x8 __attribute__((ext_vector_type(8)));
typedef float f32x4 __attribute__((ext_vector_type(4)));

typedef const __attribute__((address_space(1))) void* gptr_t;
typedef __attribute__((address_space(3))) void* lptr_t;

__device__ __forceinline__ float bf2f(short u) {
    union { float f; uint32_t i; } x;
    x.i = ((uint32_t)(uint16_t)u) << 16;
    return x.f;
}
__device__ __forceinline__ short f2bf(float f) {
    __hip_bfloat16 h = __float2bfloat16(f);  // RNE
    return *reinterpret_cast<short*>(&h);
}

// Convert all 5 f32 inputs to bf16. 8 elems/thread; segment select by flat idx.
__global__ __launch_bounds__(256)
void convert_all(const float* __restrict__ x, const float* __restrict__ wq,
                 const float* __restrict__ bq, const float* __restrict__ wo,
                 const float* __restrict__ bo,
                 short* __restrict__ xb, short* __restrict__ wqb, short* __restrict__ bqb,
                 short* __restrict__ wob, short* __restrict__ bob) {
    int i = blockIdx.x * 256 + threadIdx.x;
    const float* src; short* dst; int o;
    if      (i <  524288) { src = x;  dst = xb;  o = i; }
    else if (i <  917504) { src = wq; dst = wqb; o = i - 524288; }
    else if (i <  917888) { src = bq; dst = bqb; o = i - 917504; }
    else if (i < 1048960) { src = wo; dst = wob; o = i - 917888; }
    else if (i < 1049088) { src = bo; dst = bob; o = i - 1048960; }
    else return;
    const int e = o * 8;
    float4 a = *(const float4*)(src + e);
    float4 b = *(const float4*)(src + e + 4);
    short t[8];
    t[0] = f2bf(a.x); t[1] = f2bf(a.y); t[2] = f2bf(a.z); t[3] = f2bf(a.w);
    t[4] = f2bf(b.x); t[5] = f2bf(b.y); t[6] = f2bf(b.z); t[7] = f2bf(b.w);
    *(uint4*)(dst + e) = *(const uint4*)t;
}

// GEMM1: C[m,n] = sum_k A[m,k]*Bt[n,k] + bias[n], bf16 out. 128x128 tile, BK=32.
// Transposed acc: mfma(B,A,acc) -> lane holds m = l16-indexed row, n = quad*4+r.
__global__ __launch_bounds__(256)
void gemm_bt_128(const short* __restrict__ A, const short* __restrict__ Bt,
                 const short* __restrict__ bias, short* __restrict__ C,
                 int M, int N, int K) {
    __shared__ short As[128 * 32];  // unpadded: required by global_load_lds lane layout
    __shared__ short Bs[128 * 32];

    const int tid  = threadIdx.x;
    const int lane = tid & 63;
    const int w    = tid >> 6;
    const int qd   = lane >> 4;
    const int l16  = lane & 15;
    const int wm   = w >> 1;
    const int wn   = w & 1;
    const int mBase = blockIdx.y * 128;
    const int nBase = blockIdx.x * 128;

    f32x4 acc[4][4] = {};

    const int nK = K >> 5;
    for (int kt = 0; kt < nK; ++kt) {
        const int kb = kt << 5;
#pragma unroll
        for (int i = 0; i < 2; ++i) {
            const int e   = i * 2048 + tid * 8;
            const int row = e >> 5;
            const int col = e & 31;
            const short* ga = A  + (size_t)(mBase + row) * K + kb + col;
            const short* gb = Bt + (size_t)(nBase + row) * K + kb + col;
            lptr_t la = (lptr_t)(As + i * 2048 + w * 512);
            lptr_t lb = (lptr_t)(Bs + i * 2048 + w * 512);
            __builtin_amdgcn_global_load_lds((gptr_t)ga, la, 16, 0, 0);
            __builtin_amdgcn_global_load_lds((gptr_t)gb, lb, 16, 0, 0);
        }
        __syncthreads();

        bf16x8 af[4], bfr[4];
#pragma unroll
        for (int mi = 0; mi < 4; ++mi)
            af[mi] = *(const bf16x8*)(As + (wm * 64 + mi * 16 + l16) * 32 + qd * 8);
#pragma unroll
        for (int ni = 0; ni < 4; ++ni)
            bfr[ni] = *(const bf16x8*)(Bs + (wn * 64 + ni * 16 + l16) * 32 + qd * 8);
#pragma unroll
        for (int mi = 0; mi < 4; ++mi)
#pragma unroll
            for (int ni = 0; ni < 4; ++ni)
                acc[mi][ni] = __builtin_amdgcn_mfma_f32_16x16x32_bf16(
                    bfr[ni], af[mi], acc[mi][ni], 0, 0, 0);  // D = C^T tile
        __syncthreads();
    }

    // Lane holds C[m = ..+l16][n0..n0+3], n0 = ..+qd*4 -> packed 8B bf16 stores.
#pragma unroll
    for (int ni = 0; ni < 4; ++ni) {
        const int n0 = nBase + wn * 64 + ni * 16 + qd * 4;
        float bv[4];
#pragma unroll
        for (int r = 0; r < 4; ++r) bv[r] = bf2f(bias[n0 + r]);
#pragma unroll
        for (int mi = 0; mi < 4; ++mi) {
            const int m = mBase + wm * 64 + mi * 16 + l16;
            short t[4];
#pragma unroll
            for (int r = 0; r < 4; ++r) t[r] = f2bf(acc[mi][ni][r] + bv[r]);
            *(uint2*)&C[(size_t)m * N + n0] = *(const uint2*)t;
        }
    }
}

// GEMM2: f32 out, 64x128 tile (2 blocks/CU). Waves 2x2: 32 rows x 64 cols each.
__global__ __launch_bounds__(256)
void gemm_bt_64(const short* __restrict__ A, const short* __restrict__ Bt,
                const short* __restrict__ bias, float* __restrict__ C,
                int M, int N, int K) {
    __shared__ short As[64 * 32];    // 4 KB
    __shared__ short Bs[128 * 32];   // 8 KB

    const int tid  = threadIdx.x;
    const int lane = tid & 63;
    const int w    = tid >> 6;
    const int qd   = lane >> 4;
    const int l16  = lane & 15;
    const int wm   = w >> 1;
    const int wn   = w & 1;
    const int mBase = blockIdx.y * 64;
    const int nBase = blockIdx.x * 128;

    f32x4 acc[2][4] = {};

    const int nK = K >> 5;
    for (int kt = 0; kt < nK; ++kt) {
        const int kb = kt << 5;
        {
            const int e   = tid * 8;            // A: 64x32 = 2048 elems, one shot
            const int row = e >> 5;
            const int col = e & 31;
            const short* ga = A + (size_t)(mBase + row) * K + kb + col;
            lptr_t la = (lptr_t)(As + w * 512);
            __builtin_amdgcn_global_load_lds((gptr_t)ga, la, 16, 0, 0);
        }
#pragma unroll
        for (int i = 0; i < 2; ++i) {
            const int e   = i * 2048 + tid * 8;
            const int row = e >> 5;
            const int col = e & 31;
            const short* gb = Bt + (size_t)(nBase + row) * K + kb + col;
            lptr_t lb = (lptr_t)(Bs + i * 2048 + w * 512);
            __builtin_amdgcn_global_load_lds((gptr_t)gb, lb, 16, 0, 0);
        }
        __syncthreads();

        bf16x8 af[2], bfr[4];
#pragma unroll
        for (int mi = 0; mi < 2; ++mi)
            af[mi] = *(const bf16x8*)(As + (wm * 32 + mi * 16 + l16) * 32 + qd * 8);
#pragma unroll
        for (int ni = 0; ni < 4; ++ni)
            bfr[ni] = *(const bf16x8*)(Bs + (wn * 64 + ni * 16 + l16) * 32 + qd * 8);
#pragma unroll
        for (int mi = 0; mi < 2; ++mi)
#pragma unroll
            for (int ni = 0; ni < 4; ++ni)
                acc[mi][ni] = __builtin_amdgcn_mfma_f32_16x16x32_bf16(
                    bfr[ni], af[mi], acc[mi][ni], 0, 0, 0);  // C^T
        __syncthreads();
    }

#pragma unroll
    for (int ni = 0; ni < 4; ++ni) {
        const int n0 = nBase + wn * 64 + ni * 16 + qd * 4;
        float bv[4];
#pragma unroll
        for (int r = 0; r < 4; ++r) bv[r] = bf2f(bias[n0 + r]);
#pragma unroll
        for (int mi = 0; mi < 2; ++mi) {
            const int m = mBase + wm * 32 + mi * 16 + l16;
            f32x4 o;
#pragma unroll
            for (int r = 0; r < 4; ++r) o[r] = acc[mi][ni][r] + bv[r];
            *(f32x4*)&C[(size_t)m * N + n0] = o;   // 16B store, 64B/row segments
        }
    }
}

// MFMA attention. Block = 64 queries x 1 head x 1 batch; 256 thr = 4 waves.
__global__ __launch_bounds__(256)
void attn_mfma(const short* __restrict__ qkv, short* __restrict__ attn_out, int B, int T) {
    __shared__ short k_s[128 * 72];
    __shared__ short v_s[144 * 66];
    __shared__ short p_s[64 * 104];

    const int tid  = threadIdx.x;
    const int lane = tid & 63;
    const int w    = tid >> 6;
    const int qd   = lane >> 4;
    const int l16  = lane & 15;
    const int qs   = blockIdx.x * 64;
    const int h    = blockIdx.y;
    const int b    = blockIdx.z;
    const size_t rs   = 3072;
    const size_t base = (size_t)b * T * rs;
    const int qoff = h * 64, koff = 1024 + h * 64, voff = 2048 + h * 64;

#pragma unroll
    for (int i = 0; i < 5; ++i) {
        const int c   = tid + i * 256;
        const int row = c >> 3;
        if (row >= 144) break;
        const int ch = (c & 7) * 8;
        int gr = qs + row; if (gr > T - 1) gr = T - 1;
        uint4 uv = *(const uint4*)(qkv + base + (size_t)gr * rs + voff + ch);
        if (row < 128) {
            uint4 uk = *(const uint4*)(qkv + base + (size_t)gr * rs + koff + ch);
            *(uint4*)&k_s[row * 72 + ch] = uk;
        }
        const uint32_t* vp = (const uint32_t*)&uv;
        uint32_t* vd = (uint32_t*)&v_s[row * 66 + ch];
        vd[0] = vp[0]; vd[1] = vp[1]; vd[2] = vp[2]; vd[3] = vp[3];
    }
    __syncthreads();

    bf16x8 aq0, aq1;
    {
        const short* g = qkv + base + (size_t)(qs + 16 * w + l16) * rs + qoff + qd * 8;
        aq0 = *(const bf16x8*)(g);
        aq1 = *(const bf16x8*)(g + 32);
    }

    // QK^T: 5 key ntiles x 2 ksteps. Lane: query m = qd*4+r, key col = 16u + l16.
    f32x4 sacc[5] = {};
#pragma unroll
    for (int u = 0; u < 5; ++u) {
        const int krow = 16 * (w + u) + l16;
        bf16x8 bk0 = *(const bf16x8*)&k_s[krow * 72 + qd * 8];
        bf16x8 bk1 = *(const bf16x8*)&k_s[krow * 72 + 32 + qd * 8];
        sacc[u] = __builtin_amdgcn_mfma_f32_16x16x32_bf16(aq0, bk0, sacc[u], 0, 0, 0);
        sacc[u] = __builtin_amdgcn_mfma_f32_16x16x32_bf16(aq1, bk1, sacc[u], 0, 0, 0);
    }

    const float scale = 0.125f;
    float pw[5][4];
    float inv[4];
#pragma unroll
    for (int r = 0; r < 4; ++r) {
        const int m = 4 * qd + r;
        float mx = -3.4e38f;
#pragma unroll
        for (int u = 0; u < 5; ++u) {
            const int rel = 16 * u + l16 - m;
            const int j   = qs + 16 * (w + u) + l16;
            const bool ok = (rel >= 0) & (rel <= 64) & (j < T);
            const float v = ok ? sacc[u][r] * scale : -3.4e38f;
            pw[u][r] = v;
            mx = fmaxf(mx, v);
        }
#pragma unroll
        for (int msk = 1; msk <= 8; msk <<= 1) mx = fmaxf(mx, __shfl_xor(mx, msk));
        float sum = 0.f;
#pragma unroll
        for (int u = 0; u < 5; ++u) {
            float e = (pw[u][r] <= -3.0e38f) ? 0.f : __expf(pw[u][r] - mx);
            pw[u][r] = e;
            sum += e;
        }
#pragma unroll
        for (int msk = 1; msk <= 8; msk <<= 1) sum += __shfl_xor(sum, msk);
        inv[r] = 1.0f / sum;
    }

    // Pre-normalized P -> LDS (wave-private rows); zero strip for the padding tile.
#pragma unroll
    for (int u = 0; u < 5; ++u)
#pragma unroll
        for (int r = 0; r < 4; ++r)
            p_s[(16 * w + 4 * qd + r) * 104 + 16 * u + l16] = f2bf(pw[u][r] * inv[r]);
#pragma unroll
    for (int r = 0; r < 4; ++r)
        p_s[(16 * w + 4 * qd + r) * 104 + 80 + l16] = 0;
    // wave-private rows; same-wave RAW -> lgkmcnt wait, no barrier needed

    // PV, transposed: mfma(V-frag, P-frag) -> lane: query = l16, d = dt*16 + qd*4 + r.
    f32x4 oacc[4] = {};
#pragma unroll
    for (int ks = 0; ks < 3; ++ks) {
        bf16x8 ap = *(const bf16x8*)&p_s[(16 * w + l16) * 104 + ks * 32 + qd * 8];
#pragma unroll
        for (int dt = 0; dt < 4; ++dt) {
            short t[8];
#pragma unroll
            for (int j = 0; j < 8; ++j)
                t[j] = v_s[(16 * w + ks * 32 + qd * 8 + j) * 66 + 16 * dt + l16];
            bf16x8 bv = *(const bf16x8*)t;
            oacc[dt] = __builtin_amdgcn_mfma_f32_16x16x32_bf16(bv, ap, oacc[dt], 0, 0, 0);
        }
    }

    // Store O: 4 packed 8B stores/thread.
    const size_t row = (size_t)(b * T + qs + 16 * w + l16);
#pragma unroll
    for (int dt = 0; dt < 4; ++dt) {
        short t[4];
#pragma unroll
        for (int r = 0; r < 4; ++r) t[r] = f2bf(oacc[dt][r]);
        *(uint2*)&attn_out[row * 1024 + h * 64 + dt * 16 + qd * 4] = *(const uint2*)t;
    }
}

extern "C" void kernel_launch(void* const* d_in, const int* in_sizes, int n_in,
                              void* d_out, int out_size, void* d_ws, size_t ws_size,
                              hipStream_t stream) {
    (void)in_sizes; (void)n_in; (void)out_size; (void)ws_size;
    const int B = 2, T = 2048, D = 1024;
    const int M = B * T;  // 4096

    char* ws = (char*)d_ws;
    size_t off = 0;
    short* xb   = (short*)(ws + off); off += (size_t)M * D * 2;
    short* wqkb = (short*)(ws + off); off += (size_t)3 * D * D * 2;
    short* bqkb = (short*)(ws + off); off += (size_t)3 * D * 2;
    short* wob  = (short*)(ws + off); off += (size_t)D * D * 2;
    short* bob  = (short*)(ws + off); off += (size_t)D * 2;
    short* qkv  = (short*)(ws + off); off += (size_t)M * 3 * D * 2;
    short* attn = (short*)(ws + off); off += (size_t)M * D * 2;

    convert_all<<<dim3(4099), 256, 0, stream>>>(
        (const float*)d_in[0], (const float*)d_in[1], (const float*)d_in[2],
        (const float*)d_in[3], (const float*)d_in[4], xb, wqkb, bqkb, wob, bob);

    gemm_bt_128<<<dim3(3 * D / 128, M / 128), 256, 0, stream>>>(
        xb, wqkb, bqkb, qkv, M, 3 * D, D);
    attn_mfma<<<dim3(T / 64, 16, B), 256, 0, stream>>>(qkv, attn, B, T);
    gemm_bt_64<<<dim3(D / 128, M / 64), 256, 0, stream>>>(
        attn, wob, bob, (float*)d_out, M, D, D);
}

// Round 5
// 162.194 us; speedup vs baseline: 1.0144x; 1.0144x over previous
//
#include <hip/hip_runtime.h>
#include <hip/hip_bf16.h>
#include <stdint.h>

// LocalSlidingWindowAttention: B=2, T=2048, D=1024, H=16, hd=64, keys j in [i, i+64].
// f32 in/out. convert_all -> gemm_bt<128>(qkv) -> attn_mfma -> gemm_bt<64,f32>(out).
// GEMMs: BK=64 (32 resp. 16 MFMAs per barrier), LDS split in two [kk][row][32] halves
// to keep the m97 bank pattern while satisfying global_load_lds's base+lane*16 contract.
// Epilogue: C-layout (n = lane&15) scalar stores -> 128B wave segments (r4 packed-store regressed).

typedef short bf16x8 __attribute__((ext_vector_type(8)));
typedef float f32x4 __attribute__((ext_vector_type(4)));

typedef const __attribute__((address_space(1))) void* gptr_t;
typedef __attribute__((address_space(3))) void* lptr_t;

__device__ __forceinline__ float bf2f(short u) {
    union { float f; uint32_t i; } x;
    x.i = ((uint32_t)(uint16_t)u) << 16;
    return x.f;
}
__device__ __forceinline__ short f2bf(float f) {
    __hip_bfloat16 h = __float2bfloat16(f);  // RNE
    return *reinterpret_cast<short*>(&h);
}

// Convert all 5 f32 inputs to bf16. 8 elems/thread; segment select by flat idx.
__global__ __launch_bounds__(256)
void convert_all(const float* __restrict__ x, const float* __restrict__ wq,
                 const float* __restrict__ bq, const float* __restrict__ wo,
                 const float* __restrict__ bo,
                 short* __restrict__ xb, short* __restrict__ wqb, short* __restrict__ bqb,
                 short* __restrict__ wob, short* __restrict__ bob) {
    int i = blockIdx.x * 256 + threadIdx.x;
    const float* src; short* dst; int o;
    if      (i <  524288) { src = x;  dst = xb;  o = i; }
    else if (i <  917504) { src = wq; dst = wqb; o = i - 524288; }
    else if (i <  917888) { src = bq; dst = bqb; o = i - 917504; }
    else if (i < 1048960) { src = wo; dst = wob; o = i - 917888; }
    else if (i < 1049088) { src = bo; dst = bob; o = i - 1048960; }
    else return;
    const int e = o * 8;
    float4 a = *(const float4*)(src + e);
    float4 b = *(const float4*)(src + e + 4);
    short t[8];
    t[0] = f2bf(a.x); t[1] = f2bf(a.y); t[2] = f2bf(a.z); t[3] = f2bf(a.w);
    t[4] = f2bf(b.x); t[5] = f2bf(b.y); t[6] = f2bf(b.z); t[7] = f2bf(b.w);
    *(uint4*)(dst + e) = *(const uint4*)t;
}

// C[m,n] = sum_k A[m,k]*Bt[n,k] + bias[n]. A: MxK, Bt: NxK row-major bf16.
// Tile BM x 128, BK=64. LDS layout per tile: [kk in 0..1][row][col in 0..31] (bf16).
// Staging chunk = 16 rows x 32 cols = 512 elems = one wave's global_load_lds x16B:
//   lane l -> row r0+(l>>2), col kk*32+(l&3)*8; chunk-flat LDS offset = l*8 elems. 
template <int BM, bool OUT_F32>
__global__ __launch_bounds__(256)
void gemm_bt(const short* __restrict__ A, const short* __restrict__ Bt,
             const short* __restrict__ bias, void* __restrict__ Cv,
             int M, int N, int K) {
    __shared__ short As[BM * 64];
    __shared__ short Bs[128 * 64];
    constexpr int NMI = BM / 32;          // m-frags per wave per kstep

    const int tid  = threadIdx.x;
    const int lane = tid & 63;
    const int w    = tid >> 6;
    const int qd   = lane >> 4;
    const int l16  = lane & 15;
    const int wm   = w >> 1;              // wave row (0..1): BM/2 rows each
    const int wn   = w & 1;               // wave col: 64 cols each
    const int mBase = blockIdx.y * BM;
    const int nBase = blockIdx.x * 128;
    const int lr = lane >> 2;             // chunk row 0..15
    const int lc = (lane & 3) * 8;        // chunk col 0..31

    f32x4 acc[NMI][4] = {};

    const int nK = K >> 6;
    for (int kt = 0; kt < nK; ++kt) {
        const int kb = kt << 6;
        // A tile: BM/8 chunks, per wave BM/32.
#pragma unroll
        for (int j = 0; j < BM / 32; ++j) {
            const int c  = w * (BM / 32) + j;
            const int kk = c & 1, r0 = (c >> 1) * 16;
            const short* ga = A + (size_t)(mBase + r0 + lr) * K + kb + kk * 32 + lc;
            lptr_t la = (lptr_t)(As + kk * (BM * 32) + r0 * 32);
            __builtin_amdgcn_global_load_lds((gptr_t)ga, la, 16, 0, 0);
        }
        // B tile: 16 chunks, 4 per wave.
#pragma unroll
        for (int j = 0; j < 4; ++j) {
            const int c  = w * 4 + j;
            const int kk = c & 1, r0 = (c >> 1) * 16;
            const short* gb = Bt + (size_t)(nBase + r0 + lr) * K + kb + kk * 32 + lc;
            lptr_t lb = (lptr_t)(Bs + kk * 4096 + r0 * 32);
            __builtin_amdgcn_global_load_lds((gptr_t)gb, lb, 16, 0, 0);
        }
        __syncthreads();

#pragma unroll
        for (int kk = 0; kk < 2; ++kk) {
            bf16x8 af[NMI], bfr[4];
#pragma unroll
            for (int mi = 0; mi < NMI; ++mi)
                af[mi] = *(const bf16x8*)(As + kk * (BM * 32) +
                          (wm * (BM / 2) + mi * 16 + l16) * 32 + qd * 8);
#pragma unroll
            for (int ni = 0; ni < 4; ++ni)
                bfr[ni] = *(const bf16x8*)(Bs + kk * 4096 +
                          (wn * 64 + ni * 16 + l16) * 32 + qd * 8);
#pragma unroll
            for (int mi = 0; mi < NMI; ++mi)
#pragma unroll
                for (int ni = 0; ni < 4; ++ni)
                    acc[mi][ni] = __builtin_amdgcn_mfma_f32_16x16x32_bf16(
                        af[mi], bfr[ni], acc[mi][ni], 0, 0, 0);
        }
        __syncthreads();
    }

    // C-layout epilogue: n = ..+l16 (consecutive across lanes -> 128B segments), m = ..+qd*4+r.
#pragma unroll
    for (int ni = 0; ni < 4; ++ni) {
        const int n = nBase + wn * 64 + ni * 16 + l16;
        const float bv = bf2f(bias[n]);
#pragma unroll
        for (int mi = 0; mi < NMI; ++mi)
#pragma unroll
            for (int r = 0; r < 4; ++r) {
                const int m = mBase + wm * (BM / 2) + mi * 16 + qd * 4 + r;
                if (OUT_F32) ((float*)Cv)[(size_t)m * N + n] = acc[mi][ni][r] + bv;
                else         ((short*)Cv)[(size_t)m * N + n] = f2bf(acc[mi][ni][r] + bv);
            }
    }
}

// MFMA attention (unchanged from round 4 — passing). Block = 64 queries x head x batch.
__global__ __launch_bounds__(256)
void attn_mfma(const short* __restrict__ qkv, short* __restrict__ attn_out, int B, int T) {
    __shared__ short k_s[128 * 72];
    __shared__ short v_s[144 * 66];
    __shared__ short p_s[64 * 104];

    const int tid  = threadIdx.x;
    const int lane = tid & 63;
    const int w    = tid >> 6;
    const int qd   = lane >> 4;
    const int l16  = lane & 15;
    const int qs   = blockIdx.x * 64;
    const int h    = blockIdx.y;
    const int b    = blockIdx.z;
    const size_t rs   = 3072;
    const size_t base = (size_t)b * T * rs;
    const int qoff = h * 64, koff = 1024 + h * 64, voff = 2048 + h * 64;

#pragma unroll
    for (int i = 0; i < 5; ++i) {
        const int c   = tid + i * 256;
        const int row = c >> 3;
        if (row >= 144) break;
        const int ch = (c & 7) * 8;
        int gr = qs + row; if (gr > T - 1) gr = T - 1;
        uint4 uv = *(const uint4*)(qkv + base + (size_t)gr * rs + voff + ch);
        if (row < 128) {
            uint4 uk = *(const uint4*)(qkv + base + (size_t)gr * rs + koff + ch);
            *(uint4*)&k_s[row * 72 + ch] = uk;
        }
        const uint32_t* vp = (const uint32_t*)&uv;
        uint32_t* vd = (uint32_t*)&v_s[row * 66 + ch];
        vd[0] = vp[0]; vd[1] = vp[1]; vd[2] = vp[2]; vd[3] = vp[3];
    }
    __syncthreads();

    bf16x8 aq0, aq1;
    {
        const short* g = qkv + base + (size_t)(qs + 16 * w + l16) * rs + qoff + qd * 8;
        aq0 = *(const bf16x8*)(g);
        aq1 = *(const bf16x8*)(g + 32);
    }

    f32x4 sacc[5] = {};
#pragma unroll
    for (int u = 0; u < 5; ++u) {
        const int krow = 16 * (w + u) + l16;
        bf16x8 bk0 = *(const bf16x8*)&k_s[krow * 72 + qd * 8];
        bf16x8 bk1 = *(const bf16x8*)&k_s[krow * 72 + 32 + qd * 8];
        sacc[u] = __builtin_amdgcn_mfma_f32_16x16x32_bf16(aq0, bk0, sacc[u], 0, 0, 0);
        sacc[u] = __builtin_amdgcn_mfma_f32_16x16x32_bf16(aq1, bk1, sacc[u], 0, 0, 0);
    }

    const float scale = 0.125f;
    float pw[5][4];
    float inv[4];
#pragma unroll
    for (int r = 0; r < 4; ++r) {
        const int m = 4 * qd + r;
        float mx = -3.4e38f;
#pragma unroll
        for (int u = 0; u < 5; ++u) {
            const int rel = 16 * u + l16 - m;
            const int j   = qs + 16 * (w + u) + l16;
            const bool ok = (rel >= 0) & (rel <= 64) & (j < T);
            const float v = ok ? sacc[u][r] * scale : -3.4e38f;
            pw[u][r] = v;
            mx = fmaxf(mx, v);
        }
#pragma unroll
        for (int msk = 1; msk <= 8; msk <<= 1) mx = fmaxf(mx, __shfl_xor(mx, msk));
        float sum = 0.f;
#pragma unroll
        for (int u = 0; u < 5; ++u) {
            float e = (pw[u][r] <= -3.0e38f) ? 0.f : __expf(pw[u][r] - mx);
            pw[u][r] = e;
            sum += e;
        }
#pragma unroll
        for (int msk = 1; msk <= 8; msk <<= 1) sum += __shfl_xor(sum, msk);
        inv[r] = 1.0f / sum;
    }

#pragma unroll
    for (int u = 0; u < 5; ++u)
#pragma unroll
        for (int r = 0; r < 4; ++r)
            p_s[(16 * w + 4 * qd + r) * 104 + 16 * u + l16] = f2bf(pw[u][r] * inv[r]);
#pragma unroll
    for (int r = 0; r < 4; ++r)
        p_s[(16 * w + 4 * qd + r) * 104 + 80 + l16] = 0;
    // wave-private rows; same-wave RAW -> lgkmcnt wait, no barrier needed

    f32x4 oacc[4] = {};
#pragma unroll
    for (int ks = 0; ks < 3; ++ks) {
        bf16x8 ap = *(const bf16x8*)&p_s[(16 * w + l16) * 104 + ks * 32 + qd * 8];
#pragma unroll
        for (int dt = 0; dt < 4; ++dt) {
            short t[8];
#pragma unroll
            for (int j = 0; j < 8; ++j)
                t[j] = v_s[(16 * w + ks * 32 + qd * 8 + j) * 66 + 16 * dt + l16];
            bf16x8 bv = *(const bf16x8*)t;
            oacc[dt] = __builtin_amdgcn_mfma_f32_16x16x32_bf16(bv, ap, oacc[dt], 0, 0, 0);
        }
    }

    const size_t row = (size_t)(b * T + qs + 16 * w + l16);
#pragma unroll
    for (int dt = 0; dt < 4; ++dt) {
        short t[4];
#pragma unroll
        for (int r = 0; r < 4; ++r) t[r] = f2bf(oacc[dt][r]);
        *(uint2*)&attn_out[row * 1024 + h * 64 + dt * 16 + qd * 4] = *(const uint2*)t;
    }
}

extern "C" void kernel_launch(void* const* d_in, const int* in_sizes, int n_in,
                              void* d_out, int out_size, void* d_ws, size_t ws_size,
                              hipStream_t stream) {
    (void)in_sizes; (void)n_in; (void)out_size; (void)ws_size;
    const int B = 2, T = 2048, D = 1024;
    const int M = B * T;  // 4096

    char* ws = (char*)d_ws;
    size_t off = 0;
    short* xb   = (short*)(ws + off); off += (size_t)M * D * 2;
    short* wqkb = (short*)(ws + off); off += (size_t)3 * D * D * 2;
    short* bqkb = (short*)(ws + off); off += (size_t)3 * D * 2;
    short* wob  = (short*)(ws + off); off += (size_t)D * D * 2;
    short* bob  = (short*)(ws + off); off += (size_t)D * 2;
    short* qkv  = (short*)(ws + off); off += (size_t)M * 3 * D * 2;
    short* attn = (short*)(ws + off); off += (size_t)M * D * 2;

    convert_all<<<dim3(4099), 256, 0, stream>>>(
        (const float*)d_in[0], (const float*)d_in[1], (const float*)d_in[2],
        (const float*)d_in[3], (const float*)d_in[4], xb, wqkb, bqkb, wob, bob);

    gemm_bt<128, false><<<dim3(3 * D / 128, M / 128), 256, 0, stream>>>(
        xb, wqkb, bqkb, qkv, M, 3 * D, D);
    attn_mfma<<<dim3(T / 64, 16, B), 256, 0, stream>>>(qkv, attn, B, T);
    gemm_bt<64, true><<<dim3(D / 128, M / 64), 256, 0, stream>>>(
        attn, wob, bob, d_out, M, D, D);
}